// Round 1
// baseline (867.605 us; speedup 1.0000x reference)
//
#include <hip/hip_runtime.h>
#include <stdint.h>

typedef __bf16 bf16_t;
typedef __bf16 bf16x8 __attribute__((ext_vector_type(8)));
typedef __bf16 bf16x4 __attribute__((ext_vector_type(4)));
typedef float  f32x4  __attribute__((ext_vector_type(4)));

constexpr int cBS = 64, cP = 512, cD = 1024, cDWM = 1024, cH = 16, cHD = 64, cW = 128;
constexpr int cVTP = 672;           // padded p-extent of Vt (sp = p + 128, max used 655)
constexpr int cM = cBS * cP;        // 32768
constexpr float cSCALE = 0.125f;    // 1/sqrt(64)

__device__ __forceinline__ void gld_lds16(const void* g, void* l) {
#if __has_builtin(__builtin_amdgcn_global_load_lds)
  __builtin_amdgcn_global_load_lds(
      (__attribute__((address_space(1))) void*)g,
      (__attribute__((address_space(3))) void*)l, 16, 0, 0);
#else
  *(bf16x8*)l = *(const bf16x8*)g;  // fallback: register round-trip
#endif
}

// ---------------------------------------------------------------------------
// fp32 -> bf16 conversion of X
__global__ void cvt_x_k(const float* __restrict__ X, bf16_t* __restrict__ Y, int n) {
  int i = (blockIdx.x * blockDim.x + threadIdx.x) * 4;
  if (i >= n) return;
  float4 v = *(const float4*)(X + i);
  bf16x4 o;
  o[0] = (bf16_t)v.x; o[1] = (bf16_t)v.y; o[2] = (bf16_t)v.z; o[3] = (bf16_t)v.w;
  *(bf16x4*)(Y + i) = o;
}

// transpose + convert the four 1024x1024 weights: W[k][n] fp32 -> Wt[n][k] bf16
__global__ void cvt_wt_k(const float* __restrict__ W0, const float* __restrict__ W1,
                         const float* __restrict__ W2, const float* __restrict__ W3,
                         bf16_t* __restrict__ T0, bf16_t* __restrict__ T1,
                         bf16_t* __restrict__ T2, bf16_t* __restrict__ T3) {
  __shared__ float tile[32][33];
  const float* Wsrc; bf16_t* Tdst;
  switch (blockIdx.z) {
    case 0: Wsrc = W0; Tdst = T0; break;
    case 1: Wsrc = W1; Tdst = T1; break;
    case 2: Wsrc = W2; Tdst = T2; break;
    default: Wsrc = W3; Tdst = T3; break;
  }
  const int n0 = blockIdx.x * 32, k0 = blockIdx.y * 32;
  const int c = threadIdx.x & 31, r8 = threadIdx.x >> 5;
#pragma unroll
  for (int q = 0; q < 4; ++q) {
    int row = r8 + q * 8;
    tile[row][c] = Wsrc[(size_t)(k0 + row) * 1024 + n0 + c];
  }
  __syncthreads();
#pragma unroll
  for (int q = 0; q < 4; ++q) {
    int row = r8 + q * 8;
    Tdst[(size_t)(n0 + row) * 1024 + k0 + c] = (bf16_t)tile[c][row];
  }
}

// r[b][t] = index of last reset at-or-before t (0 if none)
__global__ void resets_k(const int* __restrict__ mask, int* __restrict__ r) {
  int b = threadIdx.x;
  if (b >= cBS) return;
  int last = 0;
  for (int t = 0; t < cP; ++t) {
    if (mask[b * cP + t] != 0) last = t;
    r[b * cP + t] = last;
  }
}

// ---------------------------------------------------------------------------
// m97-style GEMM: C[M][N] = A[M][K] (bf16, row-major) * Bt[N][K]^T + bias.
// OUT_MODE: 0 = fp32 out, 1 = bf16 out, 2 = bf16 transposed-per-head Vt layout.
template <int OUT_MODE>
__global__ __launch_bounds__(256)
void gemm_bt_k(const bf16_t* __restrict__ A, const bf16_t* __restrict__ Bt,
               const float* __restrict__ bias, void* __restrict__ Cout,
               int M, int N, int K) {
  __shared__ __align__(16) bf16_t As[2][128 * 32];
  __shared__ __align__(16) bf16_t Bs[2][128 * 32];
  const int tid = threadIdx.x;
  const int wv = tid >> 6, ln = tid & 63;
  const int ln15 = ln & 15, g4 = ln >> 4;
  const int m0 = blockIdx.y * 128, n0 = blockIdx.x * 128;
  const int wm = (wv >> 1) * 64, wn = (wv & 1) * 64;
  const bf16_t* Ab = A + (size_t)m0 * K;
  const bf16_t* Bb = Bt + (size_t)n0 * K;

  auto stage = [&](const bf16_t* G, bf16_t* L, int k0) {
#pragma unroll
    for (int g = 0; g < 2; ++g) {
      int slot = g * 256 + wv * 64 + ln;           // 512 x 16B slots, lane-ordered
      gld_lds16(G + (size_t)(slot >> 2) * K + (k0 + (slot & 3) * 8), L + slot * 8);
    }
  };

  f32x4 acc[4][4];
#pragma unroll
  for (int i = 0; i < 4; ++i)
#pragma unroll
    for (int j = 0; j < 4; ++j) acc[i][j] = {0.f, 0.f, 0.f, 0.f};

  const int nk = K >> 5;
  stage(Ab, As[0], 0);
  stage(Bb, Bs[0], 0);
  for (int kt = 0; kt < nk; ++kt) {
    __syncthreads();                                // drains vmcnt: buf[kt&1] ready
    if (kt + 1 < nk) {
      stage(Ab, As[(kt + 1) & 1], (kt + 1) * 32);
      stage(Bb, Bs[(kt + 1) & 1], (kt + 1) * 32);
    }
    const bf16_t* Asb = As[kt & 1];
    const bf16_t* Bsb = Bs[kt & 1];
    bf16x8 af[4], bfr[4];
#pragma unroll
    for (int i = 0; i < 4; ++i)
      af[i] = *(const bf16x8*)(Asb + (wm + i * 16 + ln15) * 32 + g4 * 8);
#pragma unroll
    for (int j = 0; j < 4; ++j)
      bfr[j] = *(const bf16x8*)(Bsb + (wn + j * 16 + ln15) * 32 + g4 * 8);
#pragma unroll
    for (int i = 0; i < 4; ++i)
#pragma unroll
      for (int j = 0; j < 4; ++j)
        acc[i][j] = __builtin_amdgcn_mfma_f32_16x16x32_bf16(af[i], bfr[j], acc[i][j], 0, 0, 0);
  }

  // epilogue: C row = m0+wm+i*16+g4*4+r, col = n0+wn+j*16+ln15
#pragma unroll
  for (int i = 0; i < 4; ++i) {
    const int rbase = m0 + wm + i * 16 + g4 * 4;
#pragma unroll
    for (int j = 0; j < 4; ++j) {
      const int col = n0 + wn + j * 16 + ln15;
      const float bv = bias[col];
      if constexpr (OUT_MODE == 0) {
        float* C = (float*)Cout;
#pragma unroll
        for (int r = 0; r < 4; ++r)
          C[(size_t)(rbase + r) * N + col] = acc[i][j][r] + bv;
      } else if constexpr (OUT_MODE == 1) {
        bf16_t* C = (bf16_t*)Cout;
#pragma unroll
        for (int r = 0; r < 4; ++r)
          C[(size_t)(rbase + r) * N + col] = (bf16_t)(acc[i][j][r] + bv);
      } else {
        // Vt[b][h][hd][128+p] ; row = b*512+p, col = h*64+hd ; 4 rows pack to 8B
        bf16_t* C = (bf16_t*)Cout;
        const int b = rbase >> 9, pb = rbase & 511;
        const int h = col >> 6, hd = col & 63;
        bf16x4 pk;
#pragma unroll
        for (int r = 0; r < 4; ++r) pk[r] = (bf16_t)(acc[i][j][r] + bv);
        *(bf16x4*)(C + ((size_t)((b * cH + h) * cHD + hd)) * cVTP + 128 + pb) = pk;
      }
    }
  }
}

// ---------------------------------------------------------------------------
// Windowed attention: block = (16-token tile, batch); 4 waves x 4 heads each.
__global__ __launch_bounds__(256)
void attn_k(const bf16_t* __restrict__ Q, const bf16_t* __restrict__ Kv,
            const bf16_t* __restrict__ Vt, const int* __restrict__ rr,
            bf16_t* __restrict__ O) {
  __shared__ __align__(16) bf16_t Pl[4][16][168];  // per-wave P tile, padded
  const int tid = threadIdx.x;
  const int wv = tid >> 6, ln = tid & 63, ln15 = ln & 15, g4 = ln >> 4;
  const int b = blockIdx.y, t0 = blockIdx.x * 16;
  const int sbase = t0 - 128;
  bf16_t(*Pw)[168] = Pl[wv];

  int rv[4];
#pragma unroll
  for (int r = 0; r < 4; ++r) rv[r] = rr[b * cP + t0 + g4 * 4 + r];

  for (int hi = 0; hi < 4; ++hi) {
    const int h = wv * 4 + hi;
    // Q A-frag: m = ln15 (t), k = g4*8+j (hd)
    const bf16_t* qp = Q + ((size_t)(b * cP + t0 + ln15)) * cDWM + h * cHD + g4 * 8;
    const bf16x8 qa0 = *(const bf16x8*)qp;
    const bf16x8 qa1 = *(const bf16x8*)(qp + 32);

    // QK^T over 9 s-chunks of 16 (s in [t0-128, t0+15])
    f32x4 lg[9];
#pragma unroll
    for (int c = 0; c < 9; ++c) {
      const int s = sbase + c * 16 + ln15;  // B-frag n = ln15 (s), k = hd
      bf16x8 k0v, k1v;
      if ((unsigned)s < (unsigned)cP) {
        const bf16_t* kp = Kv + ((size_t)(b * cP + s)) * cDWM + h * cHD + g4 * 8;
        k0v = *(const bf16x8*)kp;
        k1v = *(const bf16x8*)(kp + 32);
      } else {
#pragma unroll
        for (int z = 0; z < 8; ++z) { k0v[z] = (bf16_t)0.f; k1v[z] = (bf16_t)0.f; }
      }
      f32x4 a = {0.f, 0.f, 0.f, 0.f};
      a = __builtin_amdgcn_mfma_f32_16x16x32_bf16(qa0, k0v, a, 0, 0, 0);
      a = __builtin_amdgcn_mfma_f32_16x16x32_bf16(qa1, k1v, a, 0, 0, 0);
      lg[c] = a;
    }

    // mask + scale; C layout: col(s)=ln15, row(t)=g4*4+reg
    float mx[4] = {-1e30f, -1e30f, -1e30f, -1e30f};
#pragma unroll
    for (int c = 0; c < 9; ++c)
#pragma unroll
      for (int r = 0; r < 4; ++r) {
        const int s = sbase + c * 16 + ln15;
        const int t = t0 + g4 * 4 + r;
        const bool ok = (s >= rv[r]) && (s <= t) && (t - s < cW);  // rv>=0 covers s<0
        const float l = ok ? lg[c][r] * cSCALE : -1e30f;
        lg[c][r] = l;
        mx[r] = fmaxf(mx[r], l);
      }
#pragma unroll
    for (int r = 0; r < 4; ++r) {
      mx[r] = fmaxf(mx[r], __shfl_xor(mx[r], 1));
      mx[r] = fmaxf(mx[r], __shfl_xor(mx[r], 2));
      mx[r] = fmaxf(mx[r], __shfl_xor(mx[r], 4));
      mx[r] = fmaxf(mx[r], __shfl_xor(mx[r], 8));
    }
    float sm[4] = {0.f, 0.f, 0.f, 0.f};
#pragma unroll
    for (int c = 0; c < 9; ++c)
#pragma unroll
      for (int r = 0; r < 4; ++r) {
        const float e = __expf(lg[c][r] - mx[r]);
        lg[c][r] = e;
        sm[r] += e;
      }
#pragma unroll
    for (int r = 0; r < 4; ++r) {
      sm[r] += __shfl_xor(sm[r], 1);
      sm[r] += __shfl_xor(sm[r], 2);
      sm[r] += __shfl_xor(sm[r], 4);
      sm[r] += __shfl_xor(sm[r], 8);
    }
    float inv[4];
#pragma unroll
    for (int r = 0; r < 4; ++r) inv[r] = 1.f / sm[r];

    // P -> LDS (C-layout write), zero pad cols 144..159 for the 5th K-chunk
#pragma unroll
    for (int c = 0; c < 9; ++c)
#pragma unroll
      for (int r = 0; r < 4; ++r)
        Pw[g4 * 4 + r][c * 16 + ln15] = (bf16_t)(lg[c][r] * inv[r]);
#pragma unroll
    for (int z = 0; z < 4; ++z)
      Pw[ln15][144 + g4 * 4 + z] = (bf16_t)0.f;
    __syncthreads();

    // PV: A = P (m=t,k=s from LDS), B = Vt rows (n=hd, k=s contiguous)
    f32x4 oacc[4];
#pragma unroll
    for (int j = 0; j < 4; ++j) oacc[j] = {0.f, 0.f, 0.f, 0.f};
    const bf16_t* vb = Vt + ((size_t)(b * cH + h)) * cHD * cVTP;
#pragma unroll
    for (int c2 = 0; c2 < 5; ++c2) {
      const bf16x8 pa = *(const bf16x8*)(&Pw[ln15][c2 * 32 + g4 * 8]);
#pragma unroll
      for (int j = 0; j < 4; ++j) {
        const bf16x8 vf =
            *(const bf16x8*)(vb + (size_t)(j * 16 + ln15) * cVTP + (t0 + c2 * 32 + g4 * 8));
        oacc[j] = __builtin_amdgcn_mfma_f32_16x16x32_bf16(pa, vf, oacc[j], 0, 0, 0);
      }
    }
#pragma unroll
    for (int j = 0; j < 4; ++j) {
      const int col = h * cHD + j * 16 + ln15;
#pragma unroll
      for (int r = 0; r < 4; ++r)
        O[((size_t)(b * cP + t0 + g4 * 4 + r)) * cDWM + col] = (bf16_t)oacc[j][r];
    }
    __syncthreads();
  }
}

// ---------------------------------------------------------------------------
extern "C" void kernel_launch(void* const* d_in, const int* in_sizes, int n_in,
                              void* d_out, int out_size, void* d_ws, size_t ws_size,
                              hipStream_t stream) {
  (void)in_sizes; (void)n_in; (void)out_size; (void)ws_size;
  const float* x  = (const float*)d_in[0];
  const int* mask = (const int*)d_in[1];
  const float* Wq = (const float*)d_in[2];
  const float* bq = (const float*)d_in[3];
  const float* Wk = (const float*)d_in[4];
  const float* bk = (const float*)d_in[5];
  const float* Wv = (const float*)d_in[6];
  const float* bv = (const float*)d_in[7];
  const float* Wo = (const float*)d_in[8];
  const float* bo = (const float*)d_in[9];
  float* out = (float*)d_out;

  // workspace layout (~284 MiB total)
  char* ws = (char*)d_ws;
  size_t off = 0;
  bf16_t* Xbf = (bf16_t*)(ws + off); off += (size_t)cM * cD * 2;          // 64 MiB
  bf16_t* Wqt = (bf16_t*)(ws + off); off += (size_t)cD * cDWM * 2;        // 2 MiB
  bf16_t* Wkt = (bf16_t*)(ws + off); off += (size_t)cD * cDWM * 2;
  bf16_t* Wvt = (bf16_t*)(ws + off); off += (size_t)cD * cDWM * 2;
  bf16_t* Wot = (bf16_t*)(ws + off); off += (size_t)cDWM * cD * 2;
  bf16_t* Qb  = (bf16_t*)(ws + off); off += (size_t)cM * cDWM * 2;        // 64 MiB
  bf16_t* Kb  = (bf16_t*)(ws + off); off += (size_t)cM * cDWM * 2;        // 64 MiB
  bf16_t* Vt  = (bf16_t*)(ws + off); off += (size_t)cBS * cH * cHD * cVTP * 2;  // 84 MiB
  int* rbuf   = (int*)(ws + off);    off += (size_t)cBS * cP * 4;
  bf16_t* Ob  = Xbf;  // X no longer needed after the V projection

  cvt_x_k<<<(cM * cD / 4 + 255) / 256, 256, 0, stream>>>(x, Xbf, cM * cD);
  cvt_wt_k<<<dim3(32, 32, 4), 256, 0, stream>>>(Wq, Wk, Wv, Wo, Wqt, Wkt, Wvt, Wot);
  resets_k<<<1, 64, 0, stream>>>(mask, rbuf);

  dim3 gg(cDWM / 128, cM / 128);
  gemm_bt_k<1><<<gg, 256, 0, stream>>>(Xbf, Wqt, bq, Qb, cM, cDWM, cD);
  gemm_bt_k<1><<<gg, 256, 0, stream>>>(Xbf, Wkt, bk, Kb, cM, cDWM, cD);
  gemm_bt_k<2><<<gg, 256, 0, stream>>>(Xbf, Wvt, bv, Vt, cM, cDWM, cD);

  attn_k<<<dim3(cP / 16, cBS), 256, 0, stream>>>(Qb, Kb, Vt, rbuf, Ob);

  gemm_bt_k<0><<<dim3(cD / 128, cM / 128), 256, 0, stream>>>(Ob, Wot, bo, out, cM, cD, cDWM);
}

// Round 2
// 817.020 us; speedup vs baseline: 1.0619x; 1.0619x over previous
//
#include <hip/hip_runtime.h>
#include <stdint.h>

typedef __bf16 bf16_t;
typedef __bf16 bf16x8 __attribute__((ext_vector_type(8)));
typedef __bf16 bf16x4 __attribute__((ext_vector_type(4)));
typedef float  f32x4  __attribute__((ext_vector_type(4)));

constexpr int cBS = 64, cP = 512, cD = 1024, cDWM = 1024, cH = 16, cHD = 64, cW = 128;
constexpr int cVTP = 672;           // padded p-extent of Vt (sp = p + 128, max used 655)
constexpr int cM = cBS * cP;        // 32768
constexpr float cSCALE = 0.125f;    // 1/sqrt(64)

__device__ __forceinline__ void gld_lds16(const void* g, void* l) {
#if __has_builtin(__builtin_amdgcn_global_load_lds)
  __builtin_amdgcn_global_load_lds(
      (__attribute__((address_space(1))) void*)g,
      (__attribute__((address_space(3))) void*)l, 16, 0, 0);
#else
  *(bf16x8*)l = *(const bf16x8*)g;
#endif
}

// ---------------------------------------------------------------------------
// fp32 -> bf16 conversion of X
__global__ void cvt_x_k(const float* __restrict__ X, bf16_t* __restrict__ Y, int n) {
  int i = (blockIdx.x * blockDim.x + threadIdx.x) * 4;
  if (i >= n) return;
  float4 v = *(const float4*)(X + i);
  bf16x4 o;
  o[0] = (bf16_t)v.x; o[1] = (bf16_t)v.y; o[2] = (bf16_t)v.z; o[3] = (bf16_t)v.w;
  *(bf16x4*)(Y + i) = o;
}

// transpose + convert the four 1024x1024 weights: W[k][n] fp32 -> Wt[n][k] bf16
__global__ void cvt_wt_k(const float* __restrict__ W0, const float* __restrict__ W1,
                         const float* __restrict__ W2, const float* __restrict__ W3,
                         bf16_t* __restrict__ T0, bf16_t* __restrict__ T1,
                         bf16_t* __restrict__ T2, bf16_t* __restrict__ T3) {
  __shared__ float tile[32][33];
  const float* Wsrc; bf16_t* Tdst;
  switch (blockIdx.z) {
    case 0: Wsrc = W0; Tdst = T0; break;
    case 1: Wsrc = W1; Tdst = T1; break;
    case 2: Wsrc = W2; Tdst = T2; break;
    default: Wsrc = W3; Tdst = T3; break;
  }
  const int n0 = blockIdx.x * 32, k0 = blockIdx.y * 32;
  const int c = threadIdx.x & 31, r8 = threadIdx.x >> 5;
#pragma unroll
  for (int q = 0; q < 4; ++q) {
    int row = r8 + q * 8;
    tile[row][c] = Wsrc[(size_t)(k0 + row) * 1024 + n0 + c];
  }
  __syncthreads();
#pragma unroll
  for (int q = 0; q < 4; ++q) {
    int row = r8 + q * 8;
    Tdst[(size_t)(n0 + row) * 1024 + k0 + c] = (bf16_t)tile[c][row];
  }
}

// r[b][t] = index of last reset at-or-before t (0 if none)
__global__ void resets_k(const int* __restrict__ mask, int* __restrict__ r) {
  int b = threadIdx.x;
  if (b >= cBS) return;
  int last = 0;
  for (int t = 0; t < cP; ++t) {
    if (mask[b * cP + t] != 0) last = t;
    r[b * cP + t] = last;
  }
}

// ---------------------------------------------------------------------------
// Fused QKV GEMM: C[M][3072] = A[M][1024] * Wqkv_t[3072][1024]^T + bias(seg).
// Segment 0 -> Qb (bf16 row-major), 1 -> Kb, 2 -> Vt transposed-per-head.
__global__ __launch_bounds__(256)
void gemm_qkv_k(const bf16_t* __restrict__ A, const bf16_t* __restrict__ Wt,
                const float* __restrict__ bq, const float* __restrict__ bk,
                const float* __restrict__ bvv,
                bf16_t* __restrict__ Qb, bf16_t* __restrict__ Kb,
                bf16_t* __restrict__ Vt) {
  constexpr int K = 1024;
  __shared__ __align__(16) bf16_t As[2][128 * 32];
  __shared__ __align__(16) bf16_t Bs[2][128 * 32];
  const int tid = threadIdx.x;
  const int wv = tid >> 6, ln = tid & 63;
  const int ln15 = ln & 15, g4 = ln >> 4;
  const int m0 = blockIdx.y * 128, n0 = blockIdx.x * 128;
  const int wm = (wv >> 1) * 64, wn = (wv & 1) * 64;
  const bf16_t* Ab = A + (size_t)m0 * K;
  const bf16_t* Bb = Wt + (size_t)n0 * K;

  auto stage = [&](const bf16_t* G, bf16_t* L, int k0) {
#pragma unroll
    for (int g = 0; g < 2; ++g) {
      int slot = g * 256 + wv * 64 + ln;
      gld_lds16(G + (size_t)(slot >> 2) * K + (k0 + (slot & 3) * 8), L + slot * 8);
    }
  };

  f32x4 acc[4][4];
#pragma unroll
  for (int i = 0; i < 4; ++i)
#pragma unroll
    for (int j = 0; j < 4; ++j) acc[i][j] = {0.f, 0.f, 0.f, 0.f};

  const int nk = K >> 5;
  stage(Ab, As[0], 0);
  stage(Bb, Bs[0], 0);
  for (int kt = 0; kt < nk; ++kt) {
    __syncthreads();
    if (kt + 1 < nk) {
      stage(Ab, As[(kt + 1) & 1], (kt + 1) * 32);
      stage(Bb, Bs[(kt + 1) & 1], (kt + 1) * 32);
    }
    const bf16_t* Asb = As[kt & 1];
    const bf16_t* Bsb = Bs[kt & 1];
    bf16x8 af[4], bfr[4];
#pragma unroll
    for (int i = 0; i < 4; ++i)
      af[i] = *(const bf16x8*)(Asb + (wm + i * 16 + ln15) * 32 + g4 * 8);
#pragma unroll
    for (int j = 0; j < 4; ++j)
      bfr[j] = *(const bf16x8*)(Bsb + (wn + j * 16 + ln15) * 32 + g4 * 8);
#pragma unroll
    for (int i = 0; i < 4; ++i)
#pragma unroll
      for (int j = 0; j < 4; ++j)
        acc[i][j] = __builtin_amdgcn_mfma_f32_16x16x32_bf16(af[i], bfr[j], acc[i][j], 0, 0, 0);
  }

  const int seg = n0 >> 10;                  // block-uniform: 0=Q 1=K 2=V
  const float* bias = (seg == 0) ? bq : (seg == 1) ? bk : bvv;
#pragma unroll
  for (int i = 0; i < 4; ++i) {
    const int rbase = m0 + wm + i * 16 + g4 * 4;
#pragma unroll
    for (int j = 0; j < 4; ++j) {
      const int col = n0 + wn + j * 16 + ln15;
      const int cl = col & 1023;
      const float bv = bias[cl];
      if (seg == 0) {
#pragma unroll
        for (int r = 0; r < 4; ++r)
          Qb[(size_t)(rbase + r) * cDWM + cl] = (bf16_t)(acc[i][j][r] + bv);
      } else if (seg == 1) {
#pragma unroll
        for (int r = 0; r < 4; ++r)
          Kb[(size_t)(rbase + r) * cDWM + cl] = (bf16_t)(acc[i][j][r] + bv);
      } else {
        const int b = rbase >> 9, pb = rbase & 511;
        const int h = cl >> 6, hd = cl & 63;
        bf16x4 pk;
#pragma unroll
        for (int r = 0; r < 4; ++r) pk[r] = (bf16_t)(acc[i][j][r] + bv);
        *(bf16x4*)(Vt + ((size_t)((b * cH + h) * cHD + hd)) * cVTP + 128 + pb) = pk;
      }
    }
  }
}

// Output-projection GEMM (fp32 out): C[M][N] = A[M][K] * Bt[N][K]^T + bias
__global__ __launch_bounds__(256)
void gemm_bt_k(const bf16_t* __restrict__ A, const bf16_t* __restrict__ Bt,
               const float* __restrict__ bias, float* __restrict__ C,
               int M, int N, int K) {
  __shared__ __align__(16) bf16_t As[2][128 * 32];
  __shared__ __align__(16) bf16_t Bs[2][128 * 32];
  const int tid = threadIdx.x;
  const int wv = tid >> 6, ln = tid & 63;
  const int ln15 = ln & 15, g4 = ln >> 4;
  const int m0 = blockIdx.y * 128, n0 = blockIdx.x * 128;
  const int wm = (wv >> 1) * 64, wn = (wv & 1) * 64;
  const bf16_t* Ab = A + (size_t)m0 * K;
  const bf16_t* Bb = Bt + (size_t)n0 * K;

  auto stage = [&](const bf16_t* G, bf16_t* L, int k0) {
#pragma unroll
    for (int g = 0; g < 2; ++g) {
      int slot = g * 256 + wv * 64 + ln;
      gld_lds16(G + (size_t)(slot >> 2) * K + (k0 + (slot & 3) * 8), L + slot * 8);
    }
  };

  f32x4 acc[4][4];
#pragma unroll
  for (int i = 0; i < 4; ++i)
#pragma unroll
    for (int j = 0; j < 4; ++j) acc[i][j] = {0.f, 0.f, 0.f, 0.f};

  const int nk = K >> 5;
  stage(Ab, As[0], 0);
  stage(Bb, Bs[0], 0);
  for (int kt = 0; kt < nk; ++kt) {
    __syncthreads();
    if (kt + 1 < nk) {
      stage(Ab, As[(kt + 1) & 1], (kt + 1) * 32);
      stage(Bb, Bs[(kt + 1) & 1], (kt + 1) * 32);
    }
    const bf16_t* Asb = As[kt & 1];
    const bf16_t* Bsb = Bs[kt & 1];
    bf16x8 af[4], bfr[4];
#pragma unroll
    for (int i = 0; i < 4; ++i)
      af[i] = *(const bf16x8*)(Asb + (wm + i * 16 + ln15) * 32 + g4 * 8);
#pragma unroll
    for (int j = 0; j < 4; ++j)
      bfr[j] = *(const bf16x8*)(Bsb + (wn + j * 16 + ln15) * 32 + g4 * 8);
#pragma unroll
    for (int i = 0; i < 4; ++i)
#pragma unroll
      for (int j = 0; j < 4; ++j)
        acc[i][j] = __builtin_amdgcn_mfma_f32_16x16x32_bf16(af[i], bfr[j], acc[i][j], 0, 0, 0);
  }

#pragma unroll
  for (int i = 0; i < 4; ++i) {
    const int rbase = m0 + wm + i * 16 + g4 * 4;
#pragma unroll
    for (int j = 0; j < 4; ++j) {
      const int col = n0 + wn + j * 16 + ln15;
      const float bv = bias[col];
#pragma unroll
      for (int r = 0; r < 4; ++r)
        C[(size_t)(rbase + r) * N + col] = acc[i][j][r] + bv;
    }
  }
}

// ---------------------------------------------------------------------------
// Windowed attention v2: block = (head, batch); each wave owns a 16-token tile,
// 8 iterations cover 512 tokens. K window slides 64 rows/iter -> L1-resident.
// No barriers: P tiles are wave-private.
__global__ __launch_bounds__(256)
void attn2_k(const bf16_t* __restrict__ Q, const bf16_t* __restrict__ Kv,
             const bf16_t* __restrict__ Vt, const int* __restrict__ rr,
             bf16_t* __restrict__ O) {
  __shared__ __align__(16) bf16_t Pl[4][16][168];
  const int tid = threadIdx.x;
  const int wv = tid >> 6, ln = tid & 63, ln15 = ln & 15, g4 = ln >> 4;
  const int h = blockIdx.x, b = blockIdx.y;
  bf16_t(*Pw)[168] = Pl[wv];
  const bf16_t* vb = Vt + ((size_t)(b * cH + h)) * cHD * cVTP;

  for (int it = 0; it < 8; ++it) {
    const int t0 = it * 64 + wv * 16;
    const int sbase = t0 - 128;

    int rv[4];
#pragma unroll
    for (int r = 0; r < 4; ++r) rv[r] = rr[b * cP + t0 + g4 * 4 + r];

    // Q A-frag: m = ln15 (t), k = g4*8+j (hd)
    const bf16_t* qp = Q + ((size_t)(b * cP + t0 + ln15)) * cDWM + h * cHD + g4 * 8;
    const bf16x8 qa0 = *(const bf16x8*)qp;
    const bf16x8 qa1 = *(const bf16x8*)(qp + 32);

    // QK^T over 9 s-chunks of 16 (s in [t0-128, t0+15])
    f32x4 lg[9];
#pragma unroll
    for (int c = 0; c < 9; ++c) {
      const int s = sbase + c * 16 + ln15;  // B-frag n = ln15 (s), k = hd
      bf16x8 k0v, k1v;
      if ((unsigned)s < (unsigned)cP) {
        const bf16_t* kp = Kv + ((size_t)(b * cP + s)) * cDWM + h * cHD + g4 * 8;
        k0v = *(const bf16x8*)kp;
        k1v = *(const bf16x8*)(kp + 32);
      } else {
#pragma unroll
        for (int z = 0; z < 8; ++z) { k0v[z] = (bf16_t)0.f; k1v[z] = (bf16_t)0.f; }
      }
      f32x4 a = {0.f, 0.f, 0.f, 0.f};
      a = __builtin_amdgcn_mfma_f32_16x16x32_bf16(qa0, k0v, a, 0, 0, 0);
      a = __builtin_amdgcn_mfma_f32_16x16x32_bf16(qa1, k1v, a, 0, 0, 0);
      lg[c] = a;
    }

    // mask + scale; C layout: col(s)=ln15, row(t)=g4*4+reg
    float mx[4] = {-1e30f, -1e30f, -1e30f, -1e30f};
#pragma unroll
    for (int c = 0; c < 9; ++c)
#pragma unroll
      for (int r = 0; r < 4; ++r) {
        const int s = sbase + c * 16 + ln15;
        const int t = t0 + g4 * 4 + r;
        const bool ok = (s >= rv[r]) && (s <= t) && (t - s < cW);
        const float l = ok ? lg[c][r] * cSCALE : -1e30f;
        lg[c][r] = l;
        mx[r] = fmaxf(mx[r], l);
      }
#pragma unroll
    for (int r = 0; r < 4; ++r) {
      mx[r] = fmaxf(mx[r], __shfl_xor(mx[r], 1));
      mx[r] = fmaxf(mx[r], __shfl_xor(mx[r], 2));
      mx[r] = fmaxf(mx[r], __shfl_xor(mx[r], 4));
      mx[r] = fmaxf(mx[r], __shfl_xor(mx[r], 8));
    }
    float sm[4] = {0.f, 0.f, 0.f, 0.f};
#pragma unroll
    for (int c = 0; c < 9; ++c)
#pragma unroll
      for (int r = 0; r < 4; ++r) {
        const float e = __expf(lg[c][r] - mx[r]);
        lg[c][r] = e;
        sm[r] += e;
      }
#pragma unroll
    for (int r = 0; r < 4; ++r) {
      sm[r] += __shfl_xor(sm[r], 1);
      sm[r] += __shfl_xor(sm[r], 2);
      sm[r] += __shfl_xor(sm[r], 4);
      sm[r] += __shfl_xor(sm[r], 8);
    }
    float inv[4];
#pragma unroll
    for (int r = 0; r < 4; ++r) inv[r] = 1.f / sm[r];

    // P -> LDS (C-layout write), zero pad cols 144..159 for the 5th PV chunk
#pragma unroll
    for (int c = 0; c < 9; ++c)
#pragma unroll
      for (int r = 0; r < 4; ++r)
        Pw[g4 * 4 + r][c * 16 + ln15] = (bf16_t)(lg[c][r] * inv[r]);
#pragma unroll
    for (int z = 0; z < 4; ++z)
      Pw[ln15][144 + g4 * 4 + z] = (bf16_t)0.f;

    // PV: A = P (m=t, k=s from LDS), B = Vt rows (n=hd, k=s contiguous)
    f32x4 oacc[4];
#pragma unroll
    for (int j = 0; j < 4; ++j) oacc[j] = {0.f, 0.f, 0.f, 0.f};
#pragma unroll
    for (int c2 = 0; c2 < 5; ++c2) {
      const bf16x8 pa = *(const bf16x8*)(&Pw[ln15][c2 * 32 + g4 * 8]);
#pragma unroll
      for (int j = 0; j < 4; ++j) {
        const bf16x8 vf =
            *(const bf16x8*)(vb + (size_t)(j * 16 + ln15) * cVTP + (t0 + c2 * 32 + g4 * 8));
        oacc[j] = __builtin_amdgcn_mfma_f32_16x16x32_bf16(pa, vf, oacc[j], 0, 0, 0);
      }
    }
#pragma unroll
    for (int j = 0; j < 4; ++j) {
      const int col = h * cHD + j * 16 + ln15;
#pragma unroll
      for (int r = 0; r < 4; ++r)
        O[((size_t)(b * cP + t0 + g4 * 4 + r)) * cDWM + col] = (bf16_t)oacc[j][r];
    }
  }
}

// ---------------------------------------------------------------------------
extern "C" void kernel_launch(void* const* d_in, const int* in_sizes, int n_in,
                              void* d_out, int out_size, void* d_ws, size_t ws_size,
                              hipStream_t stream) {
  (void)in_sizes; (void)n_in; (void)out_size; (void)ws_size;
  const float* x  = (const float*)d_in[0];
  const int* mask = (const int*)d_in[1];
  const float* Wq = (const float*)d_in[2];
  const float* bq = (const float*)d_in[3];
  const float* Wk = (const float*)d_in[4];
  const float* bk = (const float*)d_in[5];
  const float* Wv = (const float*)d_in[6];
  const float* bv = (const float*)d_in[7];
  const float* Wo = (const float*)d_in[8];
  const float* bo = (const float*)d_in[9];
  float* out = (float*)d_out;

  char* ws = (char*)d_ws;
  size_t off = 0;
  bf16_t* Xbf = (bf16_t*)(ws + off); off += (size_t)cM * cD * 2;          // 64 MiB
  bf16_t* Wqt = (bf16_t*)(ws + off); off += (size_t)cD * cDWM * 2;        // contiguous
  bf16_t* Wkt = (bf16_t*)(ws + off); off += (size_t)cD * cDWM * 2;        //   [3072][1024]
  bf16_t* Wvt = (bf16_t*)(ws + off); off += (size_t)cD * cDWM * 2;        //   QKV block
  bf16_t* Wot = (bf16_t*)(ws + off); off += (size_t)cDWM * cD * 2;
  bf16_t* Qb  = (bf16_t*)(ws + off); off += (size_t)cM * cDWM * 2;        // 64 MiB
  bf16_t* Kb  = (bf16_t*)(ws + off); off += (size_t)cM * cDWM * 2;        // 64 MiB
  bf16_t* Vt  = (bf16_t*)(ws + off); off += (size_t)cBS * cH * cHD * cVTP * 2;  // 84 MiB
  int* rbuf   = (int*)(ws + off);    off += (size_t)cBS * cP * 4;
  bf16_t* Ob  = Xbf;  // X no longer needed after the QKV projection

  cvt_x_k<<<(cM * cD / 4 + 255) / 256, 256, 0, stream>>>(x, Xbf, cM * cD);
  cvt_wt_k<<<dim3(32, 32, 4), 256, 0, stream>>>(Wq, Wk, Wv, Wo, Wqt, Wkt, Wvt, Wot);
  resets_k<<<1, 64, 0, stream>>>(mask, rbuf);

  gemm_qkv_k<<<dim3(3 * cDWM / 128, cM / 128), 256, 0, stream>>>(
      Xbf, Wqt, bq, bk, bv, Qb, Kb, Vt);

  attn2_k<<<dim3(cH, cBS), 256, 0, stream>>>(Qb, Kb, Vt, rbuf, Ob);

  gemm_bt_k<<<dim3(cD / 128, cM / 128), 256, 0, stream>>>(Ob, Wot, bo, out, cM, cD, cDWM);
}

// Round 3
// 785.331 us; speedup vs baseline: 1.1048x; 1.0404x over previous
//
#include <hip/hip_runtime.h>
#include <stdint.h>

typedef __bf16 bf16_t;
typedef __bf16 bf16x8 __attribute__((ext_vector_type(8)));
typedef __bf16 bf16x4 __attribute__((ext_vector_type(4)));
typedef float  f32x4  __attribute__((ext_vector_type(4)));

constexpr int cBS = 64, cP = 512, cD = 1024, cDWM = 1024, cH = 16, cHD = 64, cW = 128;
constexpr int cVTP = 672;           // padded p-extent of Vt (sp = p + 128, max used 656)
constexpr int cM = cBS * cP;        // 32768
constexpr float cSCALE = 0.125f;    // 1/sqrt(64)

__device__ __forceinline__ void gld_lds16(const void* g, void* l) {
#if __has_builtin(__builtin_amdgcn_global_load_lds)
  __builtin_amdgcn_global_load_lds(
      (__attribute__((address_space(1))) void*)g,
      (__attribute__((address_space(3))) void*)l, 16, 0, 0);
#else
  *(bf16x8*)l = *(const bf16x8*)g;
#endif
}

// ---------------------------------------------------------------------------
// fp32 -> bf16 conversion of X
__global__ void cvt_x_k(const float* __restrict__ X, bf16_t* __restrict__ Y, int n) {
  int i = (blockIdx.x * blockDim.x + threadIdx.x) * 4;
  if (i >= n) return;
  float4 v = *(const float4*)(X + i);
  bf16x4 o;
  o[0] = (bf16_t)v.x; o[1] = (bf16_t)v.y; o[2] = (bf16_t)v.z; o[3] = (bf16_t)v.w;
  *(bf16x4*)(Y + i) = o;
}

// transpose + convert the four 1024x1024 weights: W[k][n] fp32 -> Wt[n][k] bf16
__global__ void cvt_wt_k(const float* __restrict__ W0, const float* __restrict__ W1,
                         const float* __restrict__ W2, const float* __restrict__ W3,
                         bf16_t* __restrict__ T0, bf16_t* __restrict__ T1,
                         bf16_t* __restrict__ T2, bf16_t* __restrict__ T3) {
  __shared__ float tile[32][33];
  const float* Wsrc; bf16_t* Tdst;
  switch (blockIdx.z) {
    case 0: Wsrc = W0; Tdst = T0; break;
    case 1: Wsrc = W1; Tdst = T1; break;
    case 2: Wsrc = W2; Tdst = T2; break;
    default: Wsrc = W3; Tdst = T3; break;
  }
  const int n0 = blockIdx.x * 32, k0 = blockIdx.y * 32;
  const int c = threadIdx.x & 31, r8 = threadIdx.x >> 5;
#pragma unroll
  for (int q = 0; q < 4; ++q) {
    int row = r8 + q * 8;
    tile[row][c] = Wsrc[(size_t)(k0 + row) * 1024 + n0 + c];
  }
  __syncthreads();
#pragma unroll
  for (int q = 0; q < 4; ++q) {
    int row = r8 + q * 8;
    Tdst[(size_t)(n0 + row) * 1024 + k0 + c] = (bf16_t)tile[c][row];
  }
}

// r[b][t] = index of last reset at-or-before t (0 if none): parallel max-scan
__global__ void resets2_k(const int* __restrict__ mask, int* __restrict__ r) {
  __shared__ int sm[cP];
  const int b = blockIdx.x, t = threadIdx.x;
  sm[t] = mask[b * cP + t] ? t : 0;
  __syncthreads();
#pragma unroll
  for (int d = 1; d < cP; d <<= 1) {
    int u = (t >= d) ? sm[t - d] : 0;
    __syncthreads();
    if (u > sm[t]) sm[t] = u;
    __syncthreads();
  }
  r[b * cP + t] = sm[t];
}

// ---------------------------------------------------------------------------
// Fused QKV GEMM, 256x128 tile: C[M][3072] = A[M][1024] * Wt[3072][1024]^T.
// Seg 0 -> Q head-major [b][h][p][hd], 1 -> K head-major, 2 -> Vt [b][h][hd][sp].
__global__ __launch_bounds__(256, 2)
void gemm_qkv2_k(const bf16_t* __restrict__ A, const bf16_t* __restrict__ Wt,
                 const float* __restrict__ bq, const float* __restrict__ bk,
                 const float* __restrict__ bvv,
                 bf16_t* __restrict__ Qh, bf16_t* __restrict__ Kh,
                 bf16_t* __restrict__ Vt) {
  constexpr int K = 1024;
  __shared__ __align__(16) bf16_t As[2][256 * 32];
  __shared__ __align__(16) bf16_t Bs[2][128 * 32];
  const int tid = threadIdx.x;
  const int wv = tid >> 6, ln = tid & 63;
  const int ln15 = ln & 15, g4 = ln >> 4;

  // XCD swizzle: per-XCD m-slice, n-fastest so A-panel is L2-resident
  const int g = blockIdx.x + 24 * blockIdx.y;   // [0, 3072)
  const int xcd = g & 7, s = g >> 3;            // s in [0, 384)
  const int nb = s % 24, mloc = s / 24;         // mloc in [0, 16)
  const int m0 = (xcd * 16 + mloc) * 256, n0 = nb * 128;

  const bf16_t* Ab = A + (size_t)m0 * K;
  const bf16_t* Bb = Wt + (size_t)n0 * K;

  auto stage = [&](int k0, int buf) {
#pragma unroll
    for (int ga = 0; ga < 4; ++ga) {
      int slot = ga * 256 + tid;                 // 1024 slots: row=slot>>2
      gld_lds16(Ab + (size_t)(slot >> 2) * K + (k0 + (slot & 3) * 8),
                As[buf] + slot * 8);
    }
#pragma unroll
    for (int gb = 0; gb < 2; ++gb) {
      int slot = gb * 256 + tid;                 // 512 slots
      gld_lds16(Bb + (size_t)(slot >> 2) * K + (k0 + (slot & 3) * 8),
                Bs[buf] + slot * 8);
    }
  };

  f32x4 acc[4][8];
#pragma unroll
  for (int i = 0; i < 4; ++i)
#pragma unroll
    for (int j = 0; j < 8; ++j) acc[i][j] = {0.f, 0.f, 0.f, 0.f};

  const int nk = K >> 5;
  stage(0, 0);
  for (int kt = 0; kt < nk; ++kt) {
    __syncthreads();
    if (kt + 1 < nk) stage((kt + 1) * 32, (kt + 1) & 1);
    const bf16_t* Asb = As[kt & 1];
    const bf16_t* Bsb = Bs[kt & 1];
    bf16x8 af[4], bfr[8];
#pragma unroll
    for (int i = 0; i < 4; ++i)
      af[i] = *(const bf16x8*)(Asb + (wv * 64 + i * 16 + ln15) * 32 + g4 * 8);
#pragma unroll
    for (int j = 0; j < 8; ++j)
      bfr[j] = *(const bf16x8*)(Bsb + (j * 16 + ln15) * 32 + g4 * 8);
#pragma unroll
    for (int i = 0; i < 4; ++i)
#pragma unroll
      for (int j = 0; j < 8; ++j)
        acc[i][j] = __builtin_amdgcn_mfma_f32_16x16x32_bf16(af[i], bfr[j], acc[i][j], 0, 0, 0);
  }

  const int seg = n0 >> 10;                      // block-uniform: 0=Q 1=K 2=V
  const float* bias = (seg == 0) ? bq : (seg == 1) ? bk : bvv;
  bf16_t* QK = (seg == 0) ? Qh : Kh;
#pragma unroll
  for (int i = 0; i < 4; ++i) {
    const int rbase = m0 + wv * 64 + i * 16 + g4 * 4;
    const int b = rbase >> 9, pb = rbase & 511;
#pragma unroll
    for (int j = 0; j < 8; ++j) {
      const int col = n0 + j * 16 + ln15;
      const int cl = col & 1023;
      const int h = cl >> 6, hd = cl & 63;
      const float bv = bias[cl];
      if (seg < 2) {
        // head-major: [b][h][p][hd]
#pragma unroll
        for (int r = 0; r < 4; ++r)
          QK[(((size_t)(b * cH + h)) * cP + pb + r) * cHD + hd] =
              (bf16_t)(acc[i][j][r] + bv);
      } else {
        bf16x4 pk;
#pragma unroll
        for (int r = 0; r < 4; ++r) pk[r] = (bf16_t)(acc[i][j][r] + bv);
        *(bf16x4*)(Vt + ((size_t)((b * cH + h) * cHD + hd)) * cVTP + 128 + pb) = pk;
      }
    }
  }
}

// Output-projection GEMM (fp32 out), 128x128 tile + XCD swizzle
__global__ __launch_bounds__(256)
void gemm_bt_k(const bf16_t* __restrict__ A, const bf16_t* __restrict__ Bt,
               const float* __restrict__ bias, float* __restrict__ C,
               int M, int N, int K) {
  __shared__ __align__(16) bf16_t As[2][128 * 32];
  __shared__ __align__(16) bf16_t Bs[2][128 * 32];
  const int tid = threadIdx.x;
  const int wv = tid >> 6, ln = tid & 63;
  const int ln15 = ln & 15, g4 = ln >> 4;

  const int g = blockIdx.x + 8 * blockIdx.y;    // [0, 2048)
  const int xcd = g & 7, s = g >> 3;            // s in [0, 256)
  const int nb = s & 7, mloc = s >> 3;          // mloc in [0, 32)
  const int m0 = (xcd * 32 + mloc) * 128, n0 = nb * 128;

  const int wm = (wv >> 1) * 64, wn = (wv & 1) * 64;
  const bf16_t* Ab = A + (size_t)m0 * K;
  const bf16_t* Bb = Bt + (size_t)n0 * K;

  auto stage = [&](const bf16_t* G, bf16_t* L, int k0) {
#pragma unroll
    for (int gg = 0; gg < 2; ++gg) {
      int slot = gg * 256 + tid;
      gld_lds16(G + (size_t)(slot >> 2) * K + (k0 + (slot & 3) * 8), L + slot * 8);
    }
  };

  f32x4 acc[4][4];
#pragma unroll
  for (int i = 0; i < 4; ++i)
#pragma unroll
    for (int j = 0; j < 4; ++j) acc[i][j] = {0.f, 0.f, 0.f, 0.f};

  const int nk = K >> 5;
  stage(Ab, As[0], 0);
  stage(Bb, Bs[0], 0);
  for (int kt = 0; kt < nk; ++kt) {
    __syncthreads();
    if (kt + 1 < nk) {
      stage(Ab, As[(kt + 1) & 1], (kt + 1) * 32);
      stage(Bb, Bs[(kt + 1) & 1], (kt + 1) * 32);
    }
    const bf16_t* Asb = As[kt & 1];
    const bf16_t* Bsb = Bs[kt & 1];
    bf16x8 af[4], bfr[4];
#pragma unroll
    for (int i = 0; i < 4; ++i)
      af[i] = *(const bf16x8*)(Asb + (wm + i * 16 + ln15) * 32 + g4 * 8);
#pragma unroll
    for (int j = 0; j < 4; ++j)
      bfr[j] = *(const bf16x8*)(Bsb + (wn + j * 16 + ln15) * 32 + g4 * 8);
#pragma unroll
    for (int i = 0; i < 4; ++i)
#pragma unroll
      for (int j = 0; j < 4; ++j)
        acc[i][j] = __builtin_amdgcn_mfma_f32_16x16x32_bf16(af[i], bfr[j], acc[i][j], 0, 0, 0);
  }

#pragma unroll
  for (int i = 0; i < 4; ++i) {
    const int rbase = m0 + wm + i * 16 + g4 * 4;
#pragma unroll
    for (int j = 0; j < 4; ++j) {
      const int col = n0 + wn + j * 16 + ln15;
      const float bv = bias[col];
#pragma unroll
      for (int r = 0; r < 4; ++r)
        C[(size_t)(rbase + r) * N + col] = acc[i][j][r] + bv;
    }
  }
}

// ---------------------------------------------------------------------------
// Windowed attention v3: block = (head, batch, t-chunk); 4 waves each own a
// 16-token tile; 2 iterations cover the 128-token chunk. Q/K head-major.
__global__ __launch_bounds__(256)
void attn3_k(const bf16_t* __restrict__ Q, const bf16_t* __restrict__ Kv,
             const bf16_t* __restrict__ Vt, const int* __restrict__ rr,
             bf16_t* __restrict__ O) {
  __shared__ __align__(16) bf16_t Pl[4][16][168];
  const int tid = threadIdx.x;
  const int wv = tid >> 6, ln = tid & 63, ln15 = ln & 15, g4 = ln >> 4;
  const int h = blockIdx.x, b = blockIdx.y, tc = blockIdx.z;
  bf16_t(*Pw)[168] = Pl[wv];
  const bf16_t* vb = Vt + ((size_t)(b * cH + h)) * cHD * cVTP;
  const bf16_t* qb = Q + ((size_t)(b * cH + h)) * cP * cHD;
  const bf16_t* kb = Kv + ((size_t)(b * cH + h)) * cP * cHD;

  for (int sub = 0; sub < 2; ++sub) {
    const int t0 = (tc * 2 + sub) * 64 + wv * 16;
    const int sbase = t0 - 128;

    int rv[4];
#pragma unroll
    for (int r = 0; r < 4; ++r) rv[r] = rr[b * cP + t0 + g4 * 4 + r];

    // Q A-frag: m = ln15 (t), k = g4*8+j (hd)
    const bf16_t* qp = qb + (size_t)(t0 + ln15) * cHD + g4 * 8;
    const bf16x8 qa0 = *(const bf16x8*)qp;
    const bf16x8 qa1 = *(const bf16x8*)(qp + 32);

    // QK^T over 9 s-chunks of 16 (s in [t0-128, t0+15])
    f32x4 lg[9];
#pragma unroll
    for (int c = 0; c < 9; ++c) {
      const int s = sbase + c * 16 + ln15;  // B-frag n = ln15 (s), k = hd
      bf16x8 k0v, k1v;
      if ((unsigned)s < (unsigned)cP) {
        const bf16_t* kp = kb + (size_t)s * cHD + g4 * 8;
        k0v = *(const bf16x8*)kp;
        k1v = *(const bf16x8*)(kp + 32);
      } else {
#pragma unroll
        for (int z = 0; z < 8; ++z) { k0v[z] = (bf16_t)0.f; k1v[z] = (bf16_t)0.f; }
      }
      f32x4 a = {0.f, 0.f, 0.f, 0.f};
      a = __builtin_amdgcn_mfma_f32_16x16x32_bf16(qa0, k0v, a, 0, 0, 0);
      a = __builtin_amdgcn_mfma_f32_16x16x32_bf16(qa1, k1v, a, 0, 0, 0);
      lg[c] = a;
    }

    // mask + scale; C layout: col(s)=ln15, row(t)=g4*4+reg
    float mx[4] = {-1e30f, -1e30f, -1e30f, -1e30f};
#pragma unroll
    for (int c = 0; c < 9; ++c)
#pragma unroll
      for (int r = 0; r < 4; ++r) {
        const int s = sbase + c * 16 + ln15;
        const int t = t0 + g4 * 4 + r;
        const bool ok = (s >= rv[r]) && (s <= t) && (t - s < cW);
        const float l = ok ? lg[c][r] * cSCALE : -1e30f;
        lg[c][r] = l;
        mx[r] = fmaxf(mx[r], l);
      }
#pragma unroll
    for (int r = 0; r < 4; ++r) {
      mx[r] = fmaxf(mx[r], __shfl_xor(mx[r], 1));
      mx[r] = fmaxf(mx[r], __shfl_xor(mx[r], 2));
      mx[r] = fmaxf(mx[r], __shfl_xor(mx[r], 4));
      mx[r] = fmaxf(mx[r], __shfl_xor(mx[r], 8));
    }
    float sm[4] = {0.f, 0.f, 0.f, 0.f};
#pragma unroll
    for (int c = 0; c < 9; ++c)
#pragma unroll
      for (int r = 0; r < 4; ++r) {
        const float e = __expf(lg[c][r] - mx[r]);
        lg[c][r] = e;
        sm[r] += e;
      }
#pragma unroll
    for (int r = 0; r < 4; ++r) {
      sm[r] += __shfl_xor(sm[r], 1);
      sm[r] += __shfl_xor(sm[r], 2);
      sm[r] += __shfl_xor(sm[r], 4);
      sm[r] += __shfl_xor(sm[r], 8);
    }
    float inv[4];
#pragma unroll
    for (int r = 0; r < 4; ++r) inv[r] = 1.f / sm[r];

    // P -> LDS (C-layout write), zero pad cols 144..159 for the 5th PV chunk
#pragma unroll
    for (int c = 0; c < 9; ++c)
#pragma unroll
      for (int r = 0; r < 4; ++r)
        Pw[g4 * 4 + r][c * 16 + ln15] = (bf16_t)(lg[c][r] * inv[r]);
#pragma unroll
    for (int z = 0; z < 4; ++z)
      Pw[ln15][144 + g4 * 4 + z] = (bf16_t)0.f;

    // PV: A = P (m=t, k=s from LDS), B = Vt rows (n=hd, k=s contiguous)
    f32x4 oacc[4];
#pragma unroll
    for (int j = 0; j < 4; ++j) oacc[j] = {0.f, 0.f, 0.f, 0.f};
#pragma unroll
    for (int c2 = 0; c2 < 5; ++c2) {
      const bf16x8 pa = *(const bf16x8*)(&Pw[ln15][c2 * 32 + g4 * 8]);
#pragma unroll
      for (int j = 0; j < 4; ++j) {
        const bf16x8 vf =
            *(const bf16x8*)(vb + (size_t)(j * 16 + ln15) * cVTP + (t0 + c2 * 32 + g4 * 8));
        oacc[j] = __builtin_amdgcn_mfma_f32_16x16x32_bf16(pa, vf, oacc[j], 0, 0, 0);
      }
    }
#pragma unroll
    for (int j = 0; j < 4; ++j) {
      const int col = h * cHD + j * 16 + ln15;
#pragma unroll
      for (int r = 0; r < 4; ++r)
        O[((size_t)(b * cP + t0 + g4 * 4 + r)) * cDWM + col] = (bf16_t)oacc[j][r];
    }
  }
}

// ---------------------------------------------------------------------------
extern "C" void kernel_launch(void* const* d_in, const int* in_sizes, int n_in,
                              void* d_out, int out_size, void* d_ws, size_t ws_size,
                              hipStream_t stream) {
  (void)in_sizes; (void)n_in; (void)out_size; (void)ws_size;
  const float* x  = (const float*)d_in[0];
  const int* mask = (const int*)d_in[1];
  const float* Wq = (const float*)d_in[2];
  const float* bq = (const float*)d_in[3];
  const float* Wk = (const float*)d_in[4];
  const float* bk = (const float*)d_in[5];
  const float* Wv = (const float*)d_in[6];
  const float* bv = (const float*)d_in[7];
  const float* Wo = (const float*)d_in[8];
  const float* bo = (const float*)d_in[9];
  float* out = (float*)d_out;

  char* ws = (char*)d_ws;
  size_t off = 0;
  bf16_t* Xbf = (bf16_t*)(ws + off); off += (size_t)cM * cD * 2;          // 64 MiB
  bf16_t* Wqt = (bf16_t*)(ws + off); off += (size_t)cD * cDWM * 2;        // contiguous
  bf16_t* Wkt = (bf16_t*)(ws + off); off += (size_t)cD * cDWM * 2;        //   [3072][1024]
  bf16_t* Wvt = (bf16_t*)(ws + off); off += (size_t)cD * cDWM * 2;        //   QKV block
  bf16_t* Wot = (bf16_t*)(ws + off); off += (size_t)cDWM * cD * 2;
  bf16_t* Qh  = (bf16_t*)(ws + off); off += (size_t)cM * cDWM * 2;        // 64 MiB
  bf16_t* Kh  = (bf16_t*)(ws + off); off += (size_t)cM * cDWM * 2;        // 64 MiB
  bf16_t* Vt  = (bf16_t*)(ws + off); off += (size_t)cBS * cH * cHD * cVTP * 2;  // 84 MiB
  int* rbuf   = (int*)(ws + off);    off += (size_t)cBS * cP * 4;
  bf16_t* Ob  = Xbf;  // X no longer needed after the QKV projection

  cvt_x_k<<<(cM * cD / 4 + 255) / 256, 256, 0, stream>>>(x, Xbf, cM * cD);
  cvt_wt_k<<<dim3(32, 32, 4), 256, 0, stream>>>(Wq, Wk, Wv, Wo, Wqt, Wkt, Wvt, Wot);
  resets2_k<<<cBS, cP, 0, stream>>>(mask, rbuf);

  gemm_qkv2_k<<<dim3(24, 128), 256, 0, stream>>>(Xbf, Wqt, bq, bk, bv, Qh, Kh, Vt);

  attn3_k<<<dim3(cH, cBS, 4), 256, 0, stream>>>(Qh, Kh, Vt, rbuf, Ob);

  gemm_bt_k<<<dim3(8, 256), 256, 0, stream>>>(Ob, Wot, bo, out, cM, cD, cDWM);
}